// Round 2
// baseline (1067.002 us; speedup 1.0000x reference)
//
#include <hip/hip_runtime.h>
#include <math.h>

// StructAttentionLayer fused kernel: B=16384, A=50, D=256, fp32.
// One block = 256 threads (4 waves) handles RPB=8 consecutive rows with a
// double-buffered register pipeline: row j+1's 13 float4 loads are issued
// before row j's attention/output phases, and barriers are raw s_barrier
// (+ lgkmcnt(0) for LDS only) so global loads stay in flight across them.
//
// Index fact: thread t's slot i holds attrs float4 at flat4 = i*256+t;
// row a = flat4>>6 = 4*i + wave (wave-uniform), chunk d4 = lane.
// => e[4i+w] is a 64-lane wave reduce; attrs stay in registers and are
// reused for the weighted output sum (single HBM pass, ~832 MiB total).

#define BN 16384
#define AN 50
#define DN 256
#define ALPHA 0.2f
#define RPB 8

__device__ __forceinline__ float wave_sum(float x) {
  x += __shfl_xor(x, 1);
  x += __shfl_xor(x, 2);
  x += __shfl_xor(x, 4);
  x += __shfl_xor(x, 8);
  x += __shfl_xor(x, 16);
  x += __shfl_xor(x, 32);
  return x;
}

__device__ __forceinline__ float wave_max(float x) {
  x = fmaxf(x, __shfl_xor(x, 1));
  x = fmaxf(x, __shfl_xor(x, 2));
  x = fmaxf(x, __shfl_xor(x, 4));
  x = fmaxf(x, __shfl_xor(x, 8));
  x = fmaxf(x, __shfl_xor(x, 16));
  x = fmaxf(x, __shfl_xor(x, 32));
  return x;
}

// LDS-write-drain + barrier + compiler fence (loads can't hoist above).
#define BARRIER()                                        \
  do {                                                   \
    asm volatile("s_waitcnt lgkmcnt(0)" ::: "memory");   \
    __builtin_amdgcn_s_barrier();                        \
    asm volatile("" ::: "memory");                       \
  } while (0)

__device__ __forceinline__ void process_row(
    const float4 (&v)[13], int bb, int t, int w, int lane, const float4& aa,
    float aent, const float* __restrict__ ent, float* __restrict__ out,
    float* e_buf, float* ent_s, float (*pbuf)[DN]) {
  // per-slot dot with a_attr chunk, then 64-lane reduce => e[4i+w]
  float p[13];
#pragma unroll
  for (int i = 0; i < 13; ++i) {
    if (i < 12 || w < 2) {
      p[i] = v[i].x * aa.x + v[i].y * aa.y + v[i].z * aa.z + v[i].w * aa.w;
      p[i] = wave_sum(p[i]);
    }
  }
  if (lane == 0) {
#pragma unroll
    for (int i = 0; i < 13; ++i) {
      if (i < 12 || w < 2) e_buf[4 * i + w] = p[i];
    }
  }
  // entity dot: one element per thread, wave reduce, cross-wave via LDS
  {
    float q = ent[(size_t)bb * DN + t] * aent;
    q = wave_sum(q);
    if (lane == 0) ent_s[w] = q;
  }
  BARRIER();  // B1: e_buf / ent_s visible to all waves

  // redundant per-wave softmax over a = lane (identical results per wave)
  float entd = ent_s[0] + ent_s[1] + ent_s[2] + ent_s[3];
  float el = (lane < AN) ? (e_buf[lane] + entd) : -1e30f;
  el = (el > 0.f) ? el : ALPHA * el;  // leaky relu
  float m = wave_max(el);
  float pe = (lane < AN) ? __expf(el - m) : 0.f;
  float s = wave_sum(pe);
  float att = pe * ((float)AN / s);

  // weighted sum reusing the registers holding attrs
  float4 o = make_float4(0.f, 0.f, 0.f, 0.f);
#pragma unroll
  for (int i = 0; i < 13; ++i) {
    if (i < 12 || w < 2) {
      float at = __shfl(att, 4 * i + w);  // wave-uniform broadcast lane
      o.x += at * v[i].x;
      o.y += at * v[i].y;
      o.z += at * v[i].z;
      o.w += at * v[i].w;
    }
  }
  reinterpret_cast<float4*>(&pbuf[w][0])[lane] = o;
  BARRIER();  // B2: pbuf visible

  float r = pbuf[0][t] + pbuf[1][t] + pbuf[2][t] + pbuf[3][t];
  out[(size_t)bb * DN + t] = r;
}

#define LOAD(vX, bb)                                                   \
  do {                                                                 \
    const float4* __restrict__ p4 = attrs4 + (size_t)(bb) * 3200;      \
    _Pragma("unroll") for (int i = 0; i < 12; ++i) vX[i] =             \
        p4[i * 256 + t];                                               \
    if (w < 2) vX[12] = p4[12 * 256 + t];                              \
  } while (0)

__global__ __launch_bounds__(256) void struct_attn_kernel(
    const float* __restrict__ attrs, const float* __restrict__ ent,
    const float* __restrict__ avec, float* __restrict__ out) {
  const int t = threadIdx.x;
  const int w = t >> 6;
  const int lane = t & 63;
  const int b0 = blockIdx.x * RPB;

  __shared__ float e_buf[AN];
  __shared__ float ent_s[4];
  __shared__ __align__(16) float pbuf[4][DN];

  const float4* attrs4 = reinterpret_cast<const float4*>(attrs);
  const float4 aa = reinterpret_cast<const float4*>(avec)[lane];  // a_attr
  const float aent = avec[DN + t];                                // a_ent[t]

  float4 vA[13], vB[13];

  LOAD(vA, b0);
#pragma unroll
  for (int j = 0; j < RPB; j += 2) {
    LOAD(vB, b0 + j + 1);  // in flight across row j's barriers
    process_row(vA, b0 + j, t, w, lane, aa, aent, ent, out, e_buf, ent_s, pbuf);
    if (j + 2 < RPB) LOAD(vA, b0 + j + 2);
    process_row(vB, b0 + j + 1, t, w, lane, aa, aent, ent, out, e_buf, ent_s, pbuf);
  }
}

extern "C" void kernel_launch(void* const* d_in, const int* in_sizes, int n_in,
                              void* d_out, int out_size, void* d_ws, size_t ws_size,
                              hipStream_t stream) {
  const float* attrs = (const float*)d_in[0];  // (B, 50, 256) f32
  const float* ent   = (const float*)d_in[1];  // (B, 256) f32
  const float* avec  = (const float*)d_in[2];  // (512, 1) f32
  float* out = (float*)d_out;                  // (B, 256) f32
  struct_attn_kernel<<<BN / RPB, 256, 0, stream>>>(attrs, ent, avec, out);
}